// Round 1
// baseline (777.388 us; speedup 1.0000x reference)
//
#include <hip/hip_runtime.h>
#include <hip/hip_bf16.h>

#define NN 50000
#define NE 800000
#define DD 128
#define HH 8
#define CC 16
#define DFF 512
#define ED 16

// ---------------- utility ----------------
__global__ void zero_int_k(int* __restrict__ a, int n) {
    int i = blockIdx.x * 256 + threadIdx.x;
    if (i < n) a[i] = 0;
}

// ---------------- CSR build ----------------
__global__ void count_k(const int* __restrict__ dst, int* __restrict__ cnt) {
    int e = blockIdx.x * 256 + threadIdx.x;
    if (e < NE) atomicAdd(&cnt[dst[e]], 1);
}

// single block, 1024 threads: exclusive scan of cnt[NN] -> row_start[NN+1]; cnt becomes cursor copy
__global__ void scan_k(int* __restrict__ cnt, int* __restrict__ row_start) {
    __shared__ int part[1024];
    int t = threadIdx.x;
    const int CH = (NN + 1023) / 1024;  // 49
    int lo = t * CH;
    int hi = lo + CH; if (hi > NN) hi = NN; if (lo > NN) lo = NN;
    int s = 0;
    for (int i = lo; i < hi; i++) s += cnt[i];
    part[t] = s;
    __syncthreads();
    for (int off = 1; off < 1024; off <<= 1) {
        int v = (t >= off) ? part[t - off] : 0;
        __syncthreads();
        part[t] += v;
        __syncthreads();
    }
    int run = part[t] - s;  // exclusive prefix
    for (int i = lo; i < hi; i++) {
        int c = cnt[i];
        row_start[i] = run;
        cnt[i] = run;   // cursor copy
        run += c;
    }
    if (t == 1023) row_start[NN] = part[1023];
}

__global__ void scatter_k(const int* __restrict__ ei, int* __restrict__ cursor,
                          int* __restrict__ e_src, int* __restrict__ perm) {
    int e = blockIdx.x * 256 + threadIdx.x;
    if (e >= NE) return;
    int s = ei[e];
    int d = ei[NE + e];
    int pos = atomicAdd(&cursor[d], 1);
    e_src[pos] = s;
    perm[e] = pos;
}

// ---------------- edge scores s_e = (ew @ We reshaped . a_e).sum ----------------
// folded: s_e[e,h] = sum_k ew[e,k] * Ae[k,h], Ae[k,h] = sum_c We[k, h*16+c]*ae[h,c]
__global__ void se_k(const float* __restrict__ ew, const float* __restrict__ We,
                     const float* __restrict__ ae, const int* __restrict__ perm,
                     float* __restrict__ s_e) {
    __shared__ float Ae[ED * HH];  // [k][h] -> Ae[k*8+h]
    int t = threadIdx.x;
    if (t < ED * HH) {
        int k = t >> 3, h = t & 7;
        float s = 0.f;
#pragma unroll
        for (int c = 0; c < CC; c++) s += We[k * DD + h * CC + c] * ae[h * CC + c];
        Ae[t] = s;
    }
    __syncthreads();
    int e = blockIdx.x * 256 + t;
    if (e >= NE) return;
    const float* ep = &ew[(size_t)e * ED];
    float4 v0 = *(const float4*)(ep);
    float4 v1 = *(const float4*)(ep + 4);
    float4 v2 = *(const float4*)(ep + 8);
    float4 v3 = *(const float4*)(ep + 12);
    float ev[16] = {v0.x, v0.y, v0.z, v0.w, v1.x, v1.y, v1.z, v1.w,
                    v2.x, v2.y, v2.z, v2.w, v3.x, v3.y, v3.z, v3.w};
    float o[8] = {0, 0, 0, 0, 0, 0, 0, 0};
#pragma unroll
    for (int k = 0; k < 16; k++) {
        float v = ev[k];
#pragma unroll
        for (int h = 0; h < 8; h++) o[h] += v * Ae[k * 8 + h];
    }
    int pp = perm[e];
    *(float4*)&s_e[(size_t)pp * 8]     = make_float4(o[0], o[1], o[2], o[3]);
    *(float4*)&s_e[(size_t)pp * 8 + 4] = make_float4(o[4], o[5], o[6], o[7]);
}

// ---------------- node GEMM: Y[n,d] = sum_k X[n,k] W[k,d] (32 nodes x 128 cols / block) ----------------
__global__ __launch_bounds__(256) void gemm_k(const float* __restrict__ X,
                                              const float* __restrict__ W,
                                              float* __restrict__ Y) {
    __shared__ float xT[128][36];  // [k][node], padded
    int t = threadIdx.x;
    int nb0 = blockIdx.x * 32;
    for (int i = t; i < 32 * 128; i += 256) {
        int k = i & 127, nb = i >> 7;
        int n = nb0 + nb;
        xT[k][nb] = (n < NN) ? X[(size_t)n * DD + k] : 0.f;
    }
    __syncthreads();
    int d = t & 127, half = t >> 7;
    float4 A0 = {0, 0, 0, 0}, A1 = {0, 0, 0, 0}, A2 = {0, 0, 0, 0}, A3 = {0, 0, 0, 0};
    for (int k = 0; k < 128; k++) {
        float w = W[k * DD + d];
        const float* xp = &xT[k][half * 16];
        float4 a0 = *(const float4*)(xp);
        float4 a1 = *(const float4*)(xp + 4);
        float4 a2 = *(const float4*)(xp + 8);
        float4 a3 = *(const float4*)(xp + 12);
        A0.x = fmaf(w, a0.x, A0.x); A0.y = fmaf(w, a0.y, A0.y);
        A0.z = fmaf(w, a0.z, A0.z); A0.w = fmaf(w, a0.w, A0.w);
        A1.x = fmaf(w, a1.x, A1.x); A1.y = fmaf(w, a1.y, A1.y);
        A1.z = fmaf(w, a1.z, A1.z); A1.w = fmaf(w, a1.w, A1.w);
        A2.x = fmaf(w, a2.x, A2.x); A2.y = fmaf(w, a2.y, A2.y);
        A2.z = fmaf(w, a2.z, A2.z); A2.w = fmaf(w, a2.w, A2.w);
        A3.x = fmaf(w, a3.x, A3.x); A3.y = fmaf(w, a3.y, A3.y);
        A3.z = fmaf(w, a3.z, A3.z); A3.w = fmaf(w, a3.w, A3.w);
    }
    float accs[16] = {A0.x, A0.y, A0.z, A0.w, A1.x, A1.y, A1.z, A1.w,
                      A2.x, A2.y, A2.z, A2.w, A3.x, A3.y, A3.z, A3.w};
    int nbase = nb0 + half * 16;
#pragma unroll
    for (int i = 0; i < 16; i++) {
        int n = nbase + i;
        if (n < NN) Y[(size_t)n * DD + d] = accs[i];
    }
}

// ---------------- s_src/s_dst from xh (exact reference reduction order) ----------------
__global__ void ssd_k(const float* __restrict__ xh, const float* __restrict__ a_src,
                      const float* __restrict__ a_dst, float* __restrict__ s_src,
                      float* __restrict__ s_dst) {
    __shared__ float as[128], ad[128];
    if (threadIdx.x < 128) {
        as[threadIdx.x] = a_src[threadIdx.x];
        ad[threadIdx.x] = a_dst[threadIdx.x];
    }
    __syncthreads();
    int idx = blockIdx.x * 256 + threadIdx.x;
    if (idx >= NN * HH) return;
    int n = idx >> 3, h = idx & 7;
    const float* x = &xh[(size_t)n * DD + h * CC];
    float s1 = 0.f, s2 = 0.f;
#pragma unroll
    for (int c = 0; c < CC; c++) {
        float v = x[c];
        s1 += v * as[h * CC + c];
        s2 += v * ad[h * CC + c];
    }
    s_src[idx] = s1;
    s_dst[idx] = s2;
}

// ---------------- aggregation: one wave per destination node ----------------
__global__ __launch_bounds__(256) void agg_k(const int* __restrict__ row_start,
                                             const int* __restrict__ e_src,
                                             const float* __restrict__ s_src,
                                             const float* __restrict__ s_dst,
                                             const float* __restrict__ s_e,
                                             const float* __restrict__ xh,
                                             float* __restrict__ out) {
    int wid = (blockIdx.x * 256 + threadIdx.x) >> 6;
    if (wid >= NN) return;
    int lane = threadIdx.x & 63;
    int h = lane >> 3;
    float sdst = s_dst[wid * 8 + h];
    int beg = row_start[wid], end = row_start[wid + 1];
    float acc0 = 0.f, acc1 = 0.f, z = 0.f;
    for (int p = beg; p < end; p++) {
        int src = e_src[p];
        float a = s_src[src * 8 + h] + sdst + s_e[(size_t)p * 8 + h];
        a = (a > 0.f) ? a : 0.2f * a;
        float ex = __expf(a);
        float2 xv = *(const float2*)&xh[(size_t)src * DD + lane * 2];
        z += ex;
        acc0 = fmaf(ex, xv.x, acc0);
        acc1 = fmaf(ex, xv.y, acc1);
    }
    float inv = 1.f / (z + 1e-16f);
    *(float2*)&out[(size_t)wid * DD + lane * 2] = make_float2(acc0 * inv, acc1 * inv);
}

// ---------------- bias + LayerNorm(ddof=1) + leaky_relu(0.01) + residual ----------------
__global__ __launch_bounds__(256) void ln_k(const float* __restrict__ hin,
                                            const float* __restrict__ bias,
                                            const float* __restrict__ g,
                                            const float* __restrict__ be,
                                            const float* __restrict__ res,
                                            float* __restrict__ out) {
    int wid = (blockIdx.x * 256 + threadIdx.x) >> 6;
    if (wid >= NN) return;
    int lane = threadIdx.x & 63;
    float2 x = *(const float2*)&hin[(size_t)wid * DD + lane * 2];
    float2 b = *(const float2*)&bias[lane * 2];
    x.x += b.x;
    x.y += b.y;
    float s = x.x + x.y;
    float q = x.x * x.x + x.y * x.y;
#pragma unroll
    for (int m = 1; m < 64; m <<= 1) {
        s += __shfl_xor(s, m, 64);
        q += __shfl_xor(q, m, 64);
    }
    float mu = s * (1.f / 128.f);
    float var = (q - 128.f * mu * mu) * (1.f / 127.f);
    float sd = sqrtf(fmaxf(var, 0.f));
    float inv = 1.f / (sd + 1e-6f);
    float2 gg = *(const float2*)&g[lane * 2];
    float2 bb = *(const float2*)&be[lane * 2];
    float y0 = gg.x * (x.x - mu) * inv + bb.x;
    float y1 = gg.y * (x.y - mu) * inv + bb.y;
    y0 = (y0 > 0.f) ? y0 : 0.01f * y0;
    y1 = (y1 > 0.f) ? y1 : 0.01f * y1;
    float2 r = *(const float2*)&res[(size_t)wid * DD + lane * 2];
    *(float2*)&out[(size_t)wid * DD + lane * 2] = make_float2(r.x + y0, r.y + y1);
}

// ---------------- fused FFN: 16 nodes / block, hidden kept in LDS ----------------
__global__ __launch_bounds__(256) void ffn_k(const float* __restrict__ X,
                                             const float* __restrict__ Wf1,
                                             const float* __restrict__ bf1,
                                             const float* __restrict__ Wf2,
                                             float* __restrict__ out) {
    __shared__ float xT[128][20];
    __shared__ float hT[512][20];
    int t = threadIdx.x;
    int nb0 = blockIdx.x * 16;
    for (int i = t; i < 16 * 128; i += 256) {
        int k = i & 127, nb = i >> 7;
        xT[k][nb] = X[(size_t)(nb0 + nb) * DD + k];
    }
    __syncthreads();
#pragma unroll
    for (int sweep = 0; sweep < 2; sweep++) {
        int u = sweep * 256 + t;
        float4 A0 = {0, 0, 0, 0}, A1 = {0, 0, 0, 0}, A2 = {0, 0, 0, 0}, A3 = {0, 0, 0, 0};
        for (int k = 0; k < 128; k++) {
            float w = Wf1[(size_t)k * DFF + u];
            const float* xp = &xT[k][0];
            float4 a0 = *(const float4*)(xp);
            float4 a1 = *(const float4*)(xp + 4);
            float4 a2 = *(const float4*)(xp + 8);
            float4 a3 = *(const float4*)(xp + 12);
            A0.x = fmaf(w, a0.x, A0.x); A0.y = fmaf(w, a0.y, A0.y);
            A0.z = fmaf(w, a0.z, A0.z); A0.w = fmaf(w, a0.w, A0.w);
            A1.x = fmaf(w, a1.x, A1.x); A1.y = fmaf(w, a1.y, A1.y);
            A1.z = fmaf(w, a1.z, A1.z); A1.w = fmaf(w, a1.w, A1.w);
            A2.x = fmaf(w, a2.x, A2.x); A2.y = fmaf(w, a2.y, A2.y);
            A2.z = fmaf(w, a2.z, A2.z); A2.w = fmaf(w, a2.w, A2.w);
            A3.x = fmaf(w, a3.x, A3.x); A3.y = fmaf(w, a3.y, A3.y);
            A3.z = fmaf(w, a3.z, A3.z); A3.w = fmaf(w, a3.w, A3.w);
        }
        float b = bf1[u];
        A0.x = fmaxf(A0.x + b, 0.f); A0.y = fmaxf(A0.y + b, 0.f);
        A0.z = fmaxf(A0.z + b, 0.f); A0.w = fmaxf(A0.w + b, 0.f);
        A1.x = fmaxf(A1.x + b, 0.f); A1.y = fmaxf(A1.y + b, 0.f);
        A1.z = fmaxf(A1.z + b, 0.f); A1.w = fmaxf(A1.w + b, 0.f);
        A2.x = fmaxf(A2.x + b, 0.f); A2.y = fmaxf(A2.y + b, 0.f);
        A2.z = fmaxf(A2.z + b, 0.f); A2.w = fmaxf(A2.w + b, 0.f);
        A3.x = fmaxf(A3.x + b, 0.f); A3.y = fmaxf(A3.y + b, 0.f);
        A3.z = fmaxf(A3.z + b, 0.f); A3.w = fmaxf(A3.w + b, 0.f);
        *(float4*)&hT[u][0]  = A0;
        *(float4*)&hT[u][4]  = A1;
        *(float4*)&hT[u][8]  = A2;
        *(float4*)&hT[u][12] = A3;
    }
    __syncthreads();
    int d = t & 127, half = t >> 7;
    float4 B0 = {0, 0, 0, 0}, B1 = {0, 0, 0, 0};
    for (int u = 0; u < 512; u++) {
        float w = Wf2[(size_t)u * DD + d];
        float4 h0 = *(const float4*)&hT[u][half * 8];
        float4 h1 = *(const float4*)&hT[u][half * 8 + 4];
        B0.x = fmaf(w, h0.x, B0.x); B0.y = fmaf(w, h0.y, B0.y);
        B0.z = fmaf(w, h0.z, B0.z); B0.w = fmaf(w, h0.w, B0.w);
        B1.x = fmaf(w, h1.x, B1.x); B1.y = fmaf(w, h1.y, B1.y);
        B1.z = fmaf(w, h1.z, B1.z); B1.w = fmaf(w, h1.w, B1.w);
    }
    float accs[8] = {B0.x, B0.y, B0.z, B0.w, B1.x, B1.y, B1.z, B1.w};
    int nbase = nb0 + half * 8;
#pragma unroll
    for (int i = 0; i < 8; i++) {
        out[(size_t)(nbase + i) * DD + d] = accs[i];
    }
}

extern "C" void kernel_launch(void* const* d_in, const int* in_sizes, int n_in,
                              void* d_out, int out_size, void* d_ws, size_t ws_size,
                              hipStream_t stream) {
    const float* nf  = (const float*)d_in[0];
    const int*   ei  = (const int*)d_in[1];
    const float* ew  = (const float*)d_in[2];
    const float* W1  = (const float*)d_in[3];
    const float* as1 = (const float*)d_in[4];
    const float* ad1 = (const float*)d_in[5];
    const float* We1 = (const float*)d_in[6];
    const float* ae1 = (const float*)d_in[7];
    const float* b1  = (const float*)d_in[8];
    const float* g1  = (const float*)d_in[9];
    const float* be1 = (const float*)d_in[10];
    const float* W2  = (const float*)d_in[11];
    const float* as2 = (const float*)d_in[12];
    const float* ad2 = (const float*)d_in[13];
    const float* We2 = (const float*)d_in[14];
    const float* ae2 = (const float*)d_in[15];
    const float* b2  = (const float*)d_in[16];
    const float* g2  = (const float*)d_in[17];
    const float* be2 = (const float*)d_in[18];
    const float* Wf1 = (const float*)d_in[19];
    const float* bf1 = (const float*)d_in[20];
    const float* Wf2 = (const float*)d_in[21];
    const float* bf2 = (const float*)d_in[22];
    const float* g3  = (const float*)d_in[23];
    const float* be3 = (const float*)d_in[24];
    float* out = (float*)d_out;

    char* p = (char*)d_ws;
    auto alloc = [&](size_t bytes) {
        char* r = p;
        p += (bytes + 255) & ~(size_t)255;
        return r;
    };
    float* nf_cur = (float*)alloc((size_t)NN * DD * 4);
    float* xh     = (float*)alloc((size_t)NN * DD * 4);
    float* h_out  = (float*)alloc((size_t)NN * DD * 4);
    float* s_e    = (float*)alloc((size_t)NE * HH * 4);
    float* s_src  = (float*)alloc((size_t)NN * HH * 4);
    float* s_dst  = (float*)alloc((size_t)NN * HH * 4);
    int* row_start = (int*)alloc((size_t)(NN + 1) * 4);
    int* cursor    = (int*)alloc((size_t)NN * 4);
    int* e_src     = (int*)alloc((size_t)NE * 4);
    int* perm      = (int*)alloc((size_t)NE * 4);

    int ebl = (NE + 255) / 256;
    int nbl = (NN + 255) / 256;

    // CSR build
    zero_int_k<<<nbl, 256, 0, stream>>>(cursor, NN);
    count_k<<<ebl, 256, 0, stream>>>(ei + NE, cursor);
    scan_k<<<1, 1024, 0, stream>>>(cursor, row_start);
    scatter_k<<<ebl, 256, 0, stream>>>(ei, cursor, e_src, perm);

    int gbl = (NN + 31) / 32;       // gemm blocks
    int wbl = (NN * 4 + 255) / 256; // wave-per-node kernels: 4 nodes/block
    wbl = (NN + 3) / 4;
    int sbl = (NN * HH + 255) / 256;

    // ---- GAT layer 1 ----
    se_k<<<ebl, 256, 0, stream>>>(ew, We1, ae1, perm, s_e);
    gemm_k<<<gbl, 256, 0, stream>>>(nf, W1, xh);
    ssd_k<<<sbl, 256, 0, stream>>>(xh, as1, ad1, s_src, s_dst);
    agg_k<<<wbl, 256, 0, stream>>>(row_start, e_src, s_src, s_dst, s_e, xh, h_out);
    ln_k<<<wbl, 256, 0, stream>>>(h_out, b1, g1, be1, nf, nf_cur);

    // ---- GAT layer 2 ----
    se_k<<<ebl, 256, 0, stream>>>(ew, We2, ae2, perm, s_e);
    gemm_k<<<gbl, 256, 0, stream>>>(nf_cur, W2, xh);
    ssd_k<<<sbl, 256, 0, stream>>>(xh, as2, ad2, s_src, s_dst);
    agg_k<<<wbl, 256, 0, stream>>>(row_start, e_src, s_src, s_dst, s_e, xh, h_out);
    ln_k<<<wbl, 256, 0, stream>>>(h_out, b2, g2, be2, nf_cur, nf_cur);

    // ---- FFN ----
    ffn_k<<<NN / 16, 256, 0, stream>>>(nf_cur, Wf1, bf1, Wf2, h_out);
    ln_k<<<wbl, 256, 0, stream>>>(h_out, bf2, g3, be3, nf_cur, out);
}